// Round 4
// baseline (423.857 us; speedup 1.0000x reference)
//
#include <hip/hip_runtime.h>
#include <math.h>

#define B 64
#define DIM 10
#define V_CH 5
#define P 50176
#define C 4

typedef float f32x4 __attribute__((ext_vector_type(4)));

// ---------------------------------------------------------------------------
// Kernel 1: compute attn[b][c] (B*C floats) into workspace.
// One block per batch b, 128 threads.  (Identical to round-2 known-good.)
// ---------------------------------------------------------------------------
__global__ __launch_bounds__(128) void attn_kernel(
    const float* __restrict__ q,   // (B,10,1)
    const float* __restrict__ k,   // (B,10,1,C)
    const float* __restrict__ md,  // (B,C)
    const float* __restrict__ qw1, const float* __restrict__ qb1,
    const float* __restrict__ qw2, const float* __restrict__ qb2,
    const float* __restrict__ qg,  const float* __restrict__ qbeta,
    const float* __restrict__ kw1, const float* __restrict__ kb1,
    const float* __restrict__ kw2, const float* __restrict__ kb2,
    const float* __restrict__ kg,  const float* __restrict__ kbeta,
    float* __restrict__ attn)      // (B,C) in d_ws
{
    const int b = blockIdx.x;
    const int t = threadIdx.x;

    __shared__ float xs[DIM];
    __shared__ float h1s[128];
    __shared__ float h2s[16];
    __shared__ float e[5][16];   // e[0]=qe, e[1..4]=ke[c]
    __shared__ float lg[4];

    for (int h = 0; h < 5; ++h) {
        const float *w1, *b1, *w2, *b2, *g, *beta;
        if (h == 0) { w1 = qw1; b1 = qb1; w2 = qw2; b2 = qb2; g = qg; beta = qbeta; }
        else        { w1 = kw1; b1 = kb1; w2 = kw2; b2 = kb2; g = kg; beta = kbeta; }

        if (t < DIM) {
            xs[t] = (h == 0) ? q[b * DIM + t]
                             : k[(b * DIM + t) * C + (h - 1)];
        }
        __syncthreads();

        // 10 -> 128 + LeakyReLU(0.1); one hidden unit per thread
        {
            float acc = b1[t];
            #pragma unroll
            for (int d = 0; d < DIM; ++d) acc += w1[t * DIM + d] * xs[d];
            h1s[t] = (acc >= 0.f) ? acc : 0.1f * acc;
        }
        __syncthreads();

        // 128 -> 16
        if (t < 16) {
            float acc = b2[t];
            #pragma unroll
            for (int i = 0; i < 128; ++i) acc += w2[t * 128 + i] * h1s[i];
            h2s[t] = acc;
        }
        __syncthreads();

        // LayerNorm(16)
        if (t < 16) {
            float mu = 0.f;
            #pragma unroll
            for (int j = 0; j < 16; ++j) mu += h2s[j];
            mu *= (1.f / 16.f);
            float var = 0.f;
            #pragma unroll
            for (int j = 0; j < 16; ++j) { float d = h2s[j] - mu; var += d * d; }
            var *= (1.f / 16.f);
            e[h][t] = (h2s[t] - mu) / sqrtf(var + 1e-5f) * g[t] + beta[t];
        }
        __syncthreads();
    }

    // logits (scale = 10^-0.5), dropout mask
    if (t < C) {
        float d = 0.f;
        #pragma unroll
        for (int j = 0; j < 16; ++j) d += e[0][j] * e[1 + t][j];
        lg[t] = d * 0.31622776601683794f - md[b * C + t] * 1e5f;
    }
    __syncthreads();

    // softmax(logits / 10) over C=4
    if (t < C) {
        float m = fmaxf(fmaxf(lg[0], lg[1]), fmaxf(lg[2], lg[3])) * 0.1f;
        float s = 0.f;
        #pragma unroll
        for (int c = 0; c < C; ++c) s += expf(lg[c] * 0.1f - m);
        attn[b * C + t] = expf(lg[t] * 0.1f - m) / s;
    }
}

// ---------------------------------------------------------------------------
// Kernel 2: out[b,vc,p] = dot(attn[b,:], v[b,vc,p,:])  and  attn_map fill.
// grid = (49, 320 + 256), block = 256.  Unit-stride assignment (round-2).
// A/B this round: v loads are PLAIN (cacheable — v is 257 MB ~ L3 size and
// constant across iterations; nt was forcing a full HBM re-fetch each iter).
// Stores stay nontemporal (out is write-once, never re-read).
// ---------------------------------------------------------------------------
__global__ __launch_bounds__(256) void wsum_kernel(
    const f32x4* __restrict__ v4,    // (B*V_CH*P) float4s (c innermost)
    const float* __restrict__ attn,  // (B,C)
    float* __restrict__ out)         // out (B*V_CH*P) then attn_map (B*C*P)
{
    const int y = blockIdx.y;
    const int t = threadIdx.x;

    if (y < B * V_CH) {
        const int b = y / V_CH;
        const f32x4 a = *(const f32x4*)(attn + b * C);
        const size_t base = (size_t)y * P + (size_t)blockIdx.x * 1024;
        #pragma unroll
        for (int i = 0; i < 4; ++i) {
            const int p = i * 256 + t;
            const f32x4 vv = v4[base + p];                 // cacheable load
            const float r = vv.x * a.x + vv.y * a.y + vv.z * a.z + vv.w * a.w;
            __builtin_nontemporal_store(r, out + base + p);
        }
    } else {
        const int idx = y - B * V_CH;          // b*C + c
        const float val = attn[idx];
        const size_t off = (size_t)(B * V_CH) * P + (size_t)idx * P
                         + (size_t)blockIdx.x * 1024 + (size_t)t * 4;
        const f32x4 r = { val, val, val, val };
        __builtin_nontemporal_store(r, (f32x4*)(out + off));
    }
}

extern "C" void kernel_launch(void* const* d_in, const int* in_sizes, int n_in,
                              void* d_out, int out_size, void* d_ws, size_t ws_size,
                              hipStream_t stream) {
    const float* q     = (const float*)d_in[0];
    const float* k     = (const float*)d_in[1];
    const float* v     = (const float*)d_in[2];
    const float* md    = (const float*)d_in[3];
    const float* qw1   = (const float*)d_in[4];
    const float* qb1   = (const float*)d_in[5];
    const float* qw2   = (const float*)d_in[6];
    const float* qb2   = (const float*)d_in[7];
    const float* qg    = (const float*)d_in[8];
    const float* qbeta = (const float*)d_in[9];
    const float* kw1   = (const float*)d_in[10];
    const float* kb1   = (const float*)d_in[11];
    const float* kw2   = (const float*)d_in[12];
    const float* kb2   = (const float*)d_in[13];
    const float* kg    = (const float*)d_in[14];
    const float* kbeta = (const float*)d_in[15];

    float* attn = (float*)d_ws;          // B*C floats
    float* out  = (float*)d_out;

    attn_kernel<<<B, 128, 0, stream>>>(q, k, md,
                                       qw1, qb1, qw2, qb2, qg, qbeta,
                                       kw1, kb1, kw2, kb2, kg, kbeta,
                                       attn);

    dim3 grid(49, B * V_CH + B * C);     // (49, 576)
    wsum_kernel<<<grid, 256, 0, stream>>>((const f32x4*)v, attn, out);
}

// Round 5
// 405.572 us; speedup vs baseline: 1.0451x; 1.0451x over previous
//
#include <hip/hip_runtime.h>
#include <math.h>

#define B 64
#define DIM 10
#define V_CH 5
#define P 50176
#define C 4

#define XCH 7                 // chunks per P-row
#define CHUNK (P / XCH)       // 7168 floats = 28*256 = 7*1024

typedef float f32x4 __attribute__((ext_vector_type(4)));

// ---------------------------------------------------------------------------
// Kernel 1: compute attn[b][c] (B*C floats) into workspace.
// One block per batch b, 128 threads.  (Identical to round-2 known-good.)
// ---------------------------------------------------------------------------
__global__ __launch_bounds__(128) void attn_kernel(
    const float* __restrict__ q,   // (B,10,1)
    const float* __restrict__ k,   // (B,10,1,C)
    const float* __restrict__ md,  // (B,C)
    const float* __restrict__ qw1, const float* __restrict__ qb1,
    const float* __restrict__ qw2, const float* __restrict__ qb2,
    const float* __restrict__ qg,  const float* __restrict__ qbeta,
    const float* __restrict__ kw1, const float* __restrict__ kb1,
    const float* __restrict__ kw2, const float* __restrict__ kb2,
    const float* __restrict__ kg,  const float* __restrict__ kbeta,
    float* __restrict__ attn)      // (B,C) in d_ws
{
    const int b = blockIdx.x;
    const int t = threadIdx.x;

    __shared__ float xs[DIM];
    __shared__ float h1s[128];
    __shared__ float h2s[16];
    __shared__ float e[5][16];   // e[0]=qe, e[1..4]=ke[c]
    __shared__ float lg[4];

    for (int h = 0; h < 5; ++h) {
        const float *w1, *b1, *w2, *b2, *g, *beta;
        if (h == 0) { w1 = qw1; b1 = qb1; w2 = qw2; b2 = qb2; g = qg; beta = qbeta; }
        else        { w1 = kw1; b1 = kb1; w2 = kw2; b2 = kb2; g = kg; beta = kbeta; }

        if (t < DIM) {
            xs[t] = (h == 0) ? q[b * DIM + t]
                             : k[(b * DIM + t) * C + (h - 1)];
        }
        __syncthreads();

        // 10 -> 128 + LeakyReLU(0.1); one hidden unit per thread
        {
            float acc = b1[t];
            #pragma unroll
            for (int d = 0; d < DIM; ++d) acc += w1[t * DIM + d] * xs[d];
            h1s[t] = (acc >= 0.f) ? acc : 0.1f * acc;
        }
        __syncthreads();

        // 128 -> 16
        if (t < 16) {
            float acc = b2[t];
            #pragma unroll
            for (int i = 0; i < 128; ++i) acc += w2[t * 128 + i] * h1s[i];
            h2s[t] = acc;
        }
        __syncthreads();

        // LayerNorm(16)
        if (t < 16) {
            float mu = 0.f;
            #pragma unroll
            for (int j = 0; j < 16; ++j) mu += h2s[j];
            mu *= (1.f / 16.f);
            float var = 0.f;
            #pragma unroll
            for (int j = 0; j < 16; ++j) { float d = h2s[j] - mu; var += d * d; }
            var *= (1.f / 16.f);
            e[h][t] = (h2s[t] - mu) / sqrtf(var + 1e-5f) * g[t] + beta[t];
        }
        __syncthreads();
    }

    // logits (scale = 10^-0.5), dropout mask
    if (t < C) {
        float d = 0.f;
        #pragma unroll
        for (int j = 0; j < 16; ++j) d += e[0][j] * e[1 + t][j];
        lg[t] = d * 0.31622776601683794f - md[b * C + t] * 1e5f;
    }
    __syncthreads();

    // softmax(logits / 10) over C=4
    if (t < C) {
        float m = fmaxf(fmaxf(lg[0], lg[1]), fmaxf(lg[2], lg[3])) * 0.1f;
        float s = 0.f;
        #pragma unroll
        for (int c = 0; c < C; ++c) s += expf(lg[c] * 0.1f - m);
        attn[b * C + t] = expf(lg[t] * 0.1f - m) / s;
    }
}

// ---------------------------------------------------------------------------
// Kernel 2: out[b,vc,p] = dot(attn[b,:], v[b,vc,p,:])  and  attn_map fill.
// grid = (7, 576), block = 256.  vs round-2: 7x coarser blocks (28 tiles per
// block instead of 4) so each wave keeps a continuously-fed pipeline of 4
// independent nt loads instead of dying after one latency ramp; 4032 blocks
// instead of 28224 cuts block-churn 7x.  Unit-stride coalescing and nt
// load/store policy identical to round-2 (the known-best).
// ---------------------------------------------------------------------------
__global__ __launch_bounds__(256) void wsum_kernel(
    const f32x4* __restrict__ v4,    // (B*V_CH*P) float4s (c innermost)
    const float* __restrict__ attn,  // (B,C)
    float* __restrict__ out)         // out (B*V_CH*P) then attn_map (B*C*P)
{
    const int y = blockIdx.y;
    const int t = threadIdx.x;

    if (y < B * V_CH) {
        const int b = y / V_CH;
        const f32x4 a = *(const f32x4*)(attn + b * C);
        const size_t base = (size_t)y * P + (size_t)blockIdx.x * CHUNK;
        for (int i = 0; i < CHUNK / 256; i += 4) {   // 28 tiles, groups of 4
            const size_t p0 = base + (size_t)(i + 0) * 256 + t;
            const size_t p1 = base + (size_t)(i + 1) * 256 + t;
            const size_t p2 = base + (size_t)(i + 2) * 256 + t;
            const size_t p3 = base + (size_t)(i + 3) * 256 + t;
            const f32x4 v0 = __builtin_nontemporal_load(v4 + p0);
            const f32x4 v1 = __builtin_nontemporal_load(v4 + p1);
            const f32x4 v2 = __builtin_nontemporal_load(v4 + p2);
            const f32x4 v3 = __builtin_nontemporal_load(v4 + p3);
            __builtin_nontemporal_store(
                v0.x * a.x + v0.y * a.y + v0.z * a.z + v0.w * a.w, out + p0);
            __builtin_nontemporal_store(
                v1.x * a.x + v1.y * a.y + v1.z * a.z + v1.w * a.w, out + p1);
            __builtin_nontemporal_store(
                v2.x * a.x + v2.y * a.y + v2.z * a.z + v2.w * a.w, out + p2);
            __builtin_nontemporal_store(
                v3.x * a.x + v3.y * a.y + v3.z * a.z + v3.w * a.w, out + p3);
        }
    } else {
        const int idx = y - B * V_CH;          // b*C + c
        const float val = attn[idx];
        float* mp = out + (size_t)(B * V_CH) * P + (size_t)idx * P
                  + (size_t)blockIdx.x * CHUNK;
        const f32x4 r = { val, val, val, val };
        #pragma unroll
        for (int i = 0; i < CHUNK / 1024; ++i)   // 7 f32x4 stores, no tail
            __builtin_nontemporal_store(r, (f32x4*)mp + i * 256 + t);
    }
}

extern "C" void kernel_launch(void* const* d_in, const int* in_sizes, int n_in,
                              void* d_out, int out_size, void* d_ws, size_t ws_size,
                              hipStream_t stream) {
    const float* q     = (const float*)d_in[0];
    const float* k     = (const float*)d_in[1];
    const float* v     = (const float*)d_in[2];
    const float* md    = (const float*)d_in[3];
    const float* qw1   = (const float*)d_in[4];
    const float* qb1   = (const float*)d_in[5];
    const float* qw2   = (const float*)d_in[6];
    const float* qb2   = (const float*)d_in[7];
    const float* qg    = (const float*)d_in[8];
    const float* qbeta = (const float*)d_in[9];
    const float* kw1   = (const float*)d_in[10];
    const float* kb1   = (const float*)d_in[11];
    const float* kw2   = (const float*)d_in[12];
    const float* kb2   = (const float*)d_in[13];
    const float* kg    = (const float*)d_in[14];
    const float* kbeta = (const float*)d_in[15];

    float* attn = (float*)d_ws;          // B*C floats
    float* out  = (float*)d_out;

    attn_kernel<<<B, 128, 0, stream>>>(q, k, md,
                                       qw1, qb1, qw2, qb2, qg, qbeta,
                                       kw1, kb1, kw2, kb2, kg, kbeta,
                                       attn);

    dim3 grid(XCH, B * V_CH + B * C);    // (7, 576)
    wsum_kernel<<<grid, 256, 0, stream>>>((const f32x4*)v, attn, out);
}

// Round 6
// 402.381 us; speedup vs baseline: 1.0534x; 1.0079x over previous
//
#include <hip/hip_runtime.h>
#include <math.h>

#define B 64
#define DIM 10
#define V_CH 5
#define P 50176
#define C 4

typedef float f32x4 __attribute__((ext_vector_type(4)));

// ---------------------------------------------------------------------------
// Kernel 1: compute attn[b][c] (B*C floats) into workspace.
// One block per batch b, 128 threads.  (Identical to round-2 known-good.)
// ---------------------------------------------------------------------------
__global__ __launch_bounds__(128) void attn_kernel(
    const float* __restrict__ q,   // (B,10,1)
    const float* __restrict__ k,   // (B,10,1,C)
    const float* __restrict__ md,  // (B,C)
    const float* __restrict__ qw1, const float* __restrict__ qb1,
    const float* __restrict__ qw2, const float* __restrict__ qb2,
    const float* __restrict__ qg,  const float* __restrict__ qbeta,
    const float* __restrict__ kw1, const float* __restrict__ kb1,
    const float* __restrict__ kw2, const float* __restrict__ kb2,
    const float* __restrict__ kg,  const float* __restrict__ kbeta,
    float* __restrict__ attn)      // (B,C) in d_ws
{
    const int b = blockIdx.x;
    const int t = threadIdx.x;

    __shared__ float xs[DIM];
    __shared__ float h1s[128];
    __shared__ float h2s[16];
    __shared__ float e[5][16];   // e[0]=qe, e[1..4]=ke[c]
    __shared__ float lg[4];

    for (int h = 0; h < 5; ++h) {
        const float *w1, *b1, *w2, *b2, *g, *beta;
        if (h == 0) { w1 = qw1; b1 = qb1; w2 = qw2; b2 = qb2; g = qg; beta = qbeta; }
        else        { w1 = kw1; b1 = kb1; w2 = kw2; b2 = kb2; g = kg; beta = kbeta; }

        if (t < DIM) {
            xs[t] = (h == 0) ? q[b * DIM + t]
                             : k[(b * DIM + t) * C + (h - 1)];
        }
        __syncthreads();

        // 10 -> 128 + LeakyReLU(0.1); one hidden unit per thread
        {
            float acc = b1[t];
            #pragma unroll
            for (int d = 0; d < DIM; ++d) acc += w1[t * DIM + d] * xs[d];
            h1s[t] = (acc >= 0.f) ? acc : 0.1f * acc;
        }
        __syncthreads();

        // 128 -> 16
        if (t < 16) {
            float acc = b2[t];
            #pragma unroll
            for (int i = 0; i < 128; ++i) acc += w2[t * 128 + i] * h1s[i];
            h2s[t] = acc;
        }
        __syncthreads();

        // LayerNorm(16)
        if (t < 16) {
            float mu = 0.f;
            #pragma unroll
            for (int j = 0; j < 16; ++j) mu += h2s[j];
            mu *= (1.f / 16.f);
            float var = 0.f;
            #pragma unroll
            for (int j = 0; j < 16; ++j) { float d = h2s[j] - mu; var += d * d; }
            var *= (1.f / 16.f);
            e[h][t] = (h2s[t] - mu) / sqrtf(var + 1e-5f) * g[t] + beta[t];
        }
        __syncthreads();
    }

    // logits (scale = 10^-0.5), dropout mask
    if (t < C) {
        float d = 0.f;
        #pragma unroll
        for (int j = 0; j < 16; ++j) d += e[0][j] * e[1 + t][j];
        lg[t] = d * 0.31622776601683794f - md[b * C + t] * 1e5f;
    }
    __syncthreads();

    // softmax(logits / 10) over C=4
    if (t < C) {
        float m = fmaxf(fmaxf(lg[0], lg[1]), fmaxf(lg[2], lg[3])) * 0.1f;
        float s = 0.f;
        #pragma unroll
        for (int c = 0; c < C; ++c) s += expf(lg[c] * 0.1f - m);
        attn[b * C + t] = expf(lg[t] * 0.1f - m) / s;
    }
}

// ---------------------------------------------------------------------------
// Kernel 2: out[b,vc,p] = dot(attn[b,:], v[b,vc,p,:])  and  attn_map fill.
// grid = (49, 576), block = 256.  Round-2 structure (known best).
// Single variable this round: stores are PLAIN (allocate in L2, full-line
// dirty writeback — lets L2 schedule write bursts around the read stream,
// like the 6.6 TB/s fill kernel).  Loads stay nontemporal (+19 us, R4).
// ---------------------------------------------------------------------------
__global__ __launch_bounds__(256) void wsum_kernel(
    const f32x4* __restrict__ v4,    // (B*V_CH*P) float4s (c innermost)
    const float* __restrict__ attn,  // (B,C)
    float* __restrict__ out)         // out (B*V_CH*P) then attn_map (B*C*P)
{
    const int y = blockIdx.y;
    const int t = threadIdx.x;

    if (y < B * V_CH) {
        const int b = y / V_CH;
        const f32x4 a = *(const f32x4*)(attn + b * C);
        const size_t base = (size_t)y * P + (size_t)blockIdx.x * 1024;
        #pragma unroll
        for (int i = 0; i < 4; ++i) {
            const int p = i * 256 + t;
            const f32x4 vv = __builtin_nontemporal_load(v4 + base + p);
            out[base + p] = vv.x * a.x + vv.y * a.y + vv.z * a.z + vv.w * a.w;
        }
    } else {
        const int idx = y - B * V_CH;          // b*C + c
        const float val = attn[idx];
        const size_t off = (size_t)(B * V_CH) * P + (size_t)idx * P
                         + (size_t)blockIdx.x * 1024 + (size_t)t * 4;
        const f32x4 r = { val, val, val, val };
        *(f32x4*)(out + off) = r;
    }
}

extern "C" void kernel_launch(void* const* d_in, const int* in_sizes, int n_in,
                              void* d_out, int out_size, void* d_ws, size_t ws_size,
                              hipStream_t stream) {
    const float* q     = (const float*)d_in[0];
    const float* k     = (const float*)d_in[1];
    const float* v     = (const float*)d_in[2];
    const float* md    = (const float*)d_in[3];
    const float* qw1   = (const float*)d_in[4];
    const float* qb1   = (const float*)d_in[5];
    const float* qw2   = (const float*)d_in[6];
    const float* qb2   = (const float*)d_in[7];
    const float* qg    = (const float*)d_in[8];
    const float* qbeta = (const float*)d_in[9];
    const float* kw1   = (const float*)d_in[10];
    const float* kb1   = (const float*)d_in[11];
    const float* kw2   = (const float*)d_in[12];
    const float* kb2   = (const float*)d_in[13];
    const float* kg    = (const float*)d_in[14];
    const float* kbeta = (const float*)d_in[15];

    float* attn = (float*)d_ws;          // B*C floats
    float* out  = (float*)d_out;

    attn_kernel<<<B, 128, 0, stream>>>(q, k, md,
                                       qw1, qb1, qw2, qb2, qg, qbeta,
                                       kw1, kb1, kw2, kb2, kg, kbeta,
                                       attn);

    dim3 grid(49, B * V_CH + B * C);     // (49, 576)
    wsum_kernel<<<grid, 256, 0, stream>>>((const f32x4*)v, attn, out);
}